// Round 16
// baseline (1407.162 us; speedup 1.0000x reference)
//
#include <hip/hip_runtime.h>
#include <hip/hip_bf16.h>
#include <math.h>

#define N_NODES 100000
#define N_EDGES 1600000
#define SCAN_B 1024
#define SCAN_NB ((N_NODES + SCAN_B - 1) / SCAN_B)

typedef _Float16 f16;
typedef f16 f16x8 __attribute__((ext_vector_type(8)));
typedef float f32x4 __attribute__((ext_vector_type(4)));
typedef unsigned short u16;
typedef u16 u16x8 __attribute__((ext_vector_type(8)));
typedef u16 u16x4 __attribute__((ext_vector_type(4)));

__device__ __forceinline__ u16 f16bits(float f) {
  union { f16 h; u16 u; } c; c.h = (f16)f; return c.u;
}
__device__ __forceinline__ float f16val(u16 b) {
  union { u16 u; f16 h; } c; c.u = b; return (float)c.h;
}

// async global->LDS, 16B per lane; LDS dest = wave-uniform base + lane*16
__device__ __forceinline__ void gload16(const void* g, void* l) {
  __builtin_amdgcn_global_load_lds(
      (const __attribute__((address_space(1))) void*)g,
      (__attribute__((address_space(3))) void*)l, 16, 0, 0);
}

// XCD pair-swizzle: ids p and p+8 (same XCD under round-robin) share a row-stripe.
__device__ __forceinline__ void pair_map(int p, int NBrow, int& row, int& col) {
  int nb = NBrow * 2;
  int cut = (nb >> 4) << 4;
  if (p < cut) { row = ((p >> 4) << 3) + (p & 7); col = (p >> 3) & 1; }
  else { int q = p - cut; row = (cut >> 1) + (q >> 1); col = q & 1; }
}

// ---------------- graph prep ----------------

__global__ void k_count(const int* __restrict__ src, const int* __restrict__ dst,
                        int* __restrict__ deg_out, int* __restrict__ deg_in) {
  int i = blockIdx.x * blockDim.x + threadIdx.x;
  int stride = gridDim.x * blockDim.x;
  for (; i < N_EDGES; i += stride) {
    atomicAdd(&deg_out[src[i]], 1);
    atomicAdd(&deg_in[dst[i]], 1);
  }
}

__global__ void k_norms(const int* __restrict__ deg_out, const int* __restrict__ deg_in,
                        float* __restrict__ norm_out, float* __restrict__ norm_in) {
  int i = blockIdx.x * blockDim.x + threadIdx.x;
  if (i < N_NODES) {
    int a = deg_out[i], b = deg_in[i];
    norm_out[i] = a > 0 ? rsqrtf((float)a) : 0.f;
    norm_in[i]  = b > 0 ? rsqrtf((float)b) : 0.f;
  }
}

// hierarchical scan: block sums -> scan sums -> local scan + base
__global__ __launch_bounds__(1024) void k_scan1(const int* __restrict__ deg,
                                                int* __restrict__ bsum) {
  __shared__ int red[16];
  int b = blockIdx.x, t = threadIdx.x;
  int i = b * SCAN_B + t;
  int x = (i < N_NODES) ? deg[i] : 0;
#pragma unroll
  for (int o = 32; o > 0; o >>= 1) x += __shfl_down(x, o, 64);
  if ((t & 63) == 0) red[t >> 6] = x;
  __syncthreads();
  if (t == 0) {
    int s = 0;
#pragma unroll
    for (int j = 0; j < 16; ++j) s += red[j];
    bsum[b] = s;
  }
}

__global__ __launch_bounds__(128) void k_scan2(const int* __restrict__ bsum,
                                               int* __restrict__ boffs) {
  __shared__ int buf[128];
  int t = threadIdx.x;
  int x = (t < SCAN_NB) ? bsum[t] : 0;
  buf[t] = x;
  __syncthreads();
  for (int off = 1; off < 128; off <<= 1) {
    int v = (t >= off) ? buf[t - off] : 0;
    __syncthreads();
    buf[t] += v;
    __syncthreads();
  }
  if (t < SCAN_NB) boffs[t] = (t > 0) ? buf[t - 1] : 0;
}

__global__ __launch_bounds__(1024) void k_scan3(const int* __restrict__ deg,
                                                const int* __restrict__ boffs,
                                                int* __restrict__ row_ptr) {
  __shared__ int buf[SCAN_B];
  int b = blockIdx.x, t = threadIdx.x;
  int i = b * SCAN_B + t;
  int x = (i < N_NODES) ? deg[i] : 0;
  buf[t] = x;
  __syncthreads();
  for (int off = 1; off < SCAN_B; off <<= 1) {
    int v = (t >= off) ? buf[t - off] : 0;
    __syncthreads();
    buf[t] += v;
    __syncthreads();
  }
  if (i < N_NODES) row_ptr[i + 1] = boffs[b] + buf[t];
  if (i == 0) row_ptr[0] = 0;
}

__global__ void k_fill(const int* __restrict__ src, const int* __restrict__ dst,
                       const int* __restrict__ row_ptr, int* __restrict__ cursor,
                       int* __restrict__ csr_src) {
  int i = blockIdx.x * blockDim.x + threadIdx.x;
  int stride = gridDim.x * blockDim.x;
  for (; i < N_EDGES; i += stride) {
    int d = dst[i];
    int p = atomicAdd(&cursor[d], 1);
    csr_src[row_ptr[d] + p] = src[i];
  }
}

// transpose + f16 convert: W[K][N] f32 -> Wt[NB][K] f16 (bits in u16)
__global__ void k_wconv(const float* __restrict__ W, int K, int N, int NB,
                        u16* __restrict__ Wt) {
  int i = blockIdx.x * blockDim.x + threadIdx.x;
  if (i >= NB * K) return;
  int col = i / K, k = i - col * K;
  float v = (col < N) ? W[(size_t)k * N + col] : 0.f;
  Wt[i] = f16bits(v);
}

// ---------------- pipelined f16 MFMA GEMM: 3-buffer, 2-deep prefetch ----------------
// LDS [buf3][block8][kchunk4][row16][8 f16]: staging (global_load_lds, lane*16)
// and fragment ds_read_b128 both linear -> zero bank conflicts. 128x128 tile,
// 4 waves (2x2), acc[4][4]. 4 gload16/wave/step; steps s+1 and s+2 in flight ->
// counted vmcnt(8), drain 8->4->0. Raw s_barrier (NOT __syncthreads).

template <int NBCOL, int OUTF32>
__global__ __launch_bounds__(256) void k_gemm_p(
    const u16* __restrict__ Ax, int K,
    const u16* __restrict__ Bx,
    void* __restrict__ Cv, int ldc, int M, int Ncols, int NBrow) {
  __shared__ u16 sA[3][8][4][16][8];
  __shared__ u16 sB[3][8][4][16][8];

  int p = blockIdx.x;
  int row, col;
  if (NBCOL == 2) pair_map(p, NBrow, row, col);
  else { row = p; col = 0; }
  int rowBase = row * 128;
  int colBase = col * 128;

  int t = threadIdx.x;
  int w = t >> 6, l = t & 63;
  int lr = l & 15;   // row within 16-row block (staging AND fragment)
  int kc = l >> 4;   // k-chunk 0..3 (16B)

  int gaR0 = min(rowBase + w * 16 + lr, M - 1);
  int gaR1 = min(rowBase + (4 + w) * 16 + lr, M - 1);
  int gbR0 = colBase + w * 16 + lr;
  int gbR1 = colBase + (4 + w) * 16 + lr;

  const u16* pA0 = Ax + (size_t)gaR0 * K + kc * 8;
  const u16* pA1 = Ax + (size_t)gaR1 * K + kc * 8;
  const u16* pB0 = Bx + (size_t)gbR0 * K + kc * 8;
  const u16* pB1 = Bx + (size_t)gbR1 * K + kc * 8;

  int wr = (w >> 1) * 64, wc = (w & 1) * 64;
  int rbA = (w >> 1) * 4;
  int rbB = (w & 1) * 4;
  int crow = kc * 4;

  f32x4 acc[4][4];
#pragma unroll
  for (int r = 0; r < 4; ++r)
#pragma unroll
    for (int c = 0; c < 4; ++c) acc[r][c] = (f32x4)(0.f);

  auto stage = [&](int bb, int k0) {
    gload16(pA0 + k0, &sA[bb][w][0][0][0]);
    gload16(pA1 + k0, &sA[bb][4 + w][0][0][0]);
    gload16(pB0 + k0, &sB[bb][w][0][0][0]);
    gload16(pB1 + k0, &sB[bb][4 + w][0][0][0]);
  };

  int NS = K >> 5;   // 8 for K=256, 16 for K=512
  stage(0, 0);
  if (1 < NS) stage(1, 32);
  for (int s = 0; s < NS; ++s) {
    int bb = s % 3;
    if (s + 2 < NS) {
      stage((s + 2) % 3, (s + 2) * 32);
      asm volatile("s_waitcnt vmcnt(8)" ::: "memory");
    } else if (s + 1 < NS) {
      asm volatile("s_waitcnt vmcnt(4)" ::: "memory");
    } else {
      asm volatile("s_waitcnt vmcnt(0)" ::: "memory");
    }
    __builtin_amdgcn_s_barrier();

    f16x8 a[4], b[4];
#pragma unroll
    for (int r = 0; r < 4; ++r) a[r] = *(const f16x8*)&sA[bb][rbA + r][kc][lr][0];
#pragma unroll
    for (int c = 0; c < 4; ++c) b[c] = *(const f16x8*)&sB[bb][rbB + c][kc][lr][0];
#pragma unroll
    for (int r = 0; r < 4; ++r)
#pragma unroll
      for (int c = 0; c < 4; ++c)
        acc[r][c] = __builtin_amdgcn_mfma_f32_16x16x32_f16(a[r], b[c], acc[r][c], 0, 0, 0);

    __builtin_amdgcn_s_barrier();
  }

#pragma unroll
  for (int r = 0; r < 4; ++r)
#pragma unroll
    for (int c = 0; c < 4; ++c) {
      int ccol = colBase + wc + c * 16 + lr;
      if (ccol < Ncols) {
#pragma unroll
        for (int j = 0; j < 4; ++j) {
          int rrow = rowBase + wr + r * 16 + crow + j;
          if (rrow < M) {
            if (OUTF32) ((float*)Cv)[(size_t)rrow * ldc + ccol] = acc[r][c][j];
            else        ((u16*)Cv)[(size_t)rrow * ldc + ccol] = f16bits(acc[r][c][j]);
          }
        }
      }
    }
}

// ---------------- layer-0 GEMM: f32 A with register prefetch ----------------
// A regs for step s+1 issued before step s's MFMA; raw s_barrier + counted
// vmcnt(4) keeps them in flight across the barrier. B staged via global_load_lds
// (issued before the A-next loads, so vmcnt(4) guarantees B landed — in-order).

__global__ __launch_bounds__(256) void k_gemm_l0(
    const float* __restrict__ Af, int K,
    const u16* __restrict__ Bx,
    const float* __restrict__ rowscale,
    u16* __restrict__ C, int ldc, int M, int Ncols, int NBrow) {
  __shared__ u16 sA[8][4][16][8];
  __shared__ u16 sB[8][4][16][8];

  int row, col;
  pair_map(blockIdx.x, NBrow, row, col);
  int rowBase = row * 128;
  int colBase = col * 128;

  int t = threadIdx.x;
  int w = t >> 6, l = t & 63;
  int lr = l & 15;
  int kc = l >> 4;

  int gaR0 = min(rowBase + w * 16 + lr, M - 1);
  int gaR1 = min(rowBase + (4 + w) * 16 + lr, M - 1);
  int gbR0 = colBase + w * 16 + lr;
  int gbR1 = colBase + (4 + w) * 16 + lr;

  const float* pA0 = Af + (size_t)gaR0 * K + kc * 8;
  const float* pA1 = Af + (size_t)gaR1 * K + kc * 8;
  float rs0 = rowscale[gaR0], rs1 = rowscale[gaR1];

  int wr = (w >> 1) * 64, wc = (w & 1) * 64;
  int rbA = (w >> 1) * 4;
  int rbB = (w & 1) * 4;
  int crow = kc * 4;

  f32x4 acc[4][4];
#pragma unroll
  for (int r = 0; r < 4; ++r)
#pragma unroll
    for (int c = 0; c < 4; ++c) acc[r][c] = (f32x4)(0.f);

  // prologue: A regs for step 0
  float4 r00 = *(const float4*)(pA0);
  float4 r01 = *(const float4*)(pA0 + 4);
  float4 r10 = *(const float4*)(pA1);
  float4 r11 = *(const float4*)(pA1 + 4);

  int NS = K >> 5;
  for (int s = 0; s < NS; ++s) {
    int k0 = s * 32;
    __builtin_amdgcn_s_barrier();                       // protect LDS reuse
    asm volatile("s_waitcnt vmcnt(0)" ::: "memory");    // A regs for step s landed
    u16x8 h;
    h[0] = f16bits(r00.x * rs0); h[1] = f16bits(r00.y * rs0);
    h[2] = f16bits(r00.z * rs0); h[3] = f16bits(r00.w * rs0);
    h[4] = f16bits(r01.x * rs0); h[5] = f16bits(r01.y * rs0);
    h[6] = f16bits(r01.z * rs0); h[7] = f16bits(r01.w * rs0);
    *(u16x8*)&sA[w][kc][lr][0] = h;
    h[0] = f16bits(r10.x * rs1); h[1] = f16bits(r10.y * rs1);
    h[2] = f16bits(r10.z * rs1); h[3] = f16bits(r10.w * rs1);
    h[4] = f16bits(r11.x * rs1); h[5] = f16bits(r11.y * rs1);
    h[6] = f16bits(r11.z * rs1); h[7] = f16bits(r11.w * rs1);
    *(u16x8*)&sA[4 + w][kc][lr][0] = h;
    gload16(Bx + (size_t)gbR0 * K + k0 + kc * 8, &sB[w][0][0][0]);
    gload16(Bx + (size_t)gbR1 * K + k0 + kc * 8, &sB[4 + w][0][0][0]);
    if (s + 1 < NS) {
      int kn = k0 + 32;
      r00 = *(const float4*)(pA0 + kn);
      r01 = *(const float4*)(pA0 + kn + 4);
      r10 = *(const float4*)(pA1 + kn);
      r11 = *(const float4*)(pA1 + kn + 4);
      asm volatile("s_waitcnt vmcnt(4) lgkmcnt(0)" ::: "memory");  // B landed; 4 A-next in flight
    } else {
      asm volatile("s_waitcnt vmcnt(0) lgkmcnt(0)" ::: "memory");
    }
    __builtin_amdgcn_s_barrier();

    f16x8 a[4], b[4];
#pragma unroll
    for (int r = 0; r < 4; ++r) a[r] = *(const f16x8*)&sA[rbA + r][kc][lr][0];
#pragma unroll
    for (int c = 0; c < 4; ++c) b[c] = *(const f16x8*)&sB[rbB + c][kc][lr][0];
#pragma unroll
    for (int r = 0; r < 4; ++r)
#pragma unroll
      for (int c = 0; c < 4; ++c)
        acc[r][c] = __builtin_amdgcn_mfma_f32_16x16x32_f16(a[r], b[c], acc[r][c], 0, 0, 0);
  }

#pragma unroll
  for (int r = 0; r < 4; ++r)
#pragma unroll
    for (int c = 0; c < 4; ++c) {
      int ccol = colBase + wc + c * 16 + lr;
      if (ccol < Ncols) {
#pragma unroll
        for (int j = 0; j < 4; ++j) {
          int rrow = rowBase + wr + r * 16 + crow + j;
          if (rrow < M) C[(size_t)rrow * ldc + ccol] = f16bits(acc[r][c][j]);
        }
      }
    }
}

// ---------------- CSR aggregation: wave per node, lane owns 4 cols ----------------
// proj is f16 (8B/lane/edge gather, 8-edge unroll); f32 accum.
// mode 0: jk = v.  mode 1: jk = max(jk,v).  mode 2: jv = max(jk,v), planes from jv.
// plane hF = (sel value) * norm_out, f16 — ready as next GEMM's A.

__global__ __launch_bounds__(256) void k_agg(const u16* __restrict__ proj,
                                             const int* __restrict__ row_ptr,
                                             const int* __restrict__ csr_src,
                                             const float* __restrict__ norm_in,
                                             const float* __restrict__ norm_out,
                                             const float* __restrict__ bias,
                                             u16* __restrict__ hF,
                                             u16* __restrict__ jk, int mode) {
  int wid = __builtin_amdgcn_readfirstlane(threadIdx.x >> 6);
  int node = blockIdx.x * 4 + wid;
  if (node >= N_NODES) return;
  int l4 = (threadIdx.x & 63) * 4;

  int s = row_ptr[node], e = row_ptr[node + 1];
  f32x4 a0 = (f32x4)(0.f), a1 = (f32x4)(0.f), a2 = (f32x4)(0.f), a3 = (f32x4)(0.f);
  int i = s;
  for (; i + 7 < e; i += 8) {
    int u0 = csr_src[i + 0], u1 = csr_src[i + 1], u2 = csr_src[i + 2], u3 = csr_src[i + 3];
    int u4 = csr_src[i + 4], u5 = csr_src[i + 5], u6 = csr_src[i + 6], u7 = csr_src[i + 7];
    u16x4 r0 = *(const u16x4*)(proj + (size_t)u0 * 256 + l4);
    u16x4 r1 = *(const u16x4*)(proj + (size_t)u1 * 256 + l4);
    u16x4 r2 = *(const u16x4*)(proj + (size_t)u2 * 256 + l4);
    u16x4 r3 = *(const u16x4*)(proj + (size_t)u3 * 256 + l4);
    u16x4 r4 = *(const u16x4*)(proj + (size_t)u4 * 256 + l4);
    u16x4 r5 = *(const u16x4*)(proj + (size_t)u5 * 256 + l4);
    u16x4 r6 = *(const u16x4*)(proj + (size_t)u6 * 256 + l4);
    u16x4 r7 = *(const u16x4*)(proj + (size_t)u7 * 256 + l4);
#pragma unroll
    for (int j = 0; j < 4; ++j) {
      a0[j] += f16val(r0[j]) + f16val(r4[j]);
      a1[j] += f16val(r1[j]) + f16val(r5[j]);
      a2[j] += f16val(r2[j]) + f16val(r6[j]);
      a3[j] += f16val(r3[j]) + f16val(r7[j]);
    }
  }
  for (; i + 3 < e; i += 4) {
    int u0 = csr_src[i + 0], u1 = csr_src[i + 1], u2 = csr_src[i + 2], u3 = csr_src[i + 3];
    u16x4 r0 = *(const u16x4*)(proj + (size_t)u0 * 256 + l4);
    u16x4 r1 = *(const u16x4*)(proj + (size_t)u1 * 256 + l4);
    u16x4 r2 = *(const u16x4*)(proj + (size_t)u2 * 256 + l4);
    u16x4 r3 = *(const u16x4*)(proj + (size_t)u3 * 256 + l4);
#pragma unroll
    for (int j = 0; j < 4; ++j) {
      a0[j] += f16val(r0[j]);
      a1[j] += f16val(r1[j]);
      a2[j] += f16val(r2[j]);
      a3[j] += f16val(r3[j]);
    }
  }
  for (; i < e; ++i) {
    u16x4 r0 = *(const u16x4*)(proj + (size_t)csr_src[i] * 256 + l4);
#pragma unroll
    for (int j = 0; j < 4; ++j) a0[j] += f16val(r0[j]);
  }

  float nin = norm_in[node];
  f32x4 b4 = *(const f32x4*)(bias + l4);
  f32x4 v = ((a0 + a1) + (a2 + a3)) * nin + b4;
#pragma unroll
  for (int j = 0; j < 4; ++j) v[j] = fmaxf(v[j], 0.f);

  size_t idx = (size_t)node * 256 + l4;
  f32x4 pv = v;
  if (mode == 0) {
    u16x4 jw;
#pragma unroll
    for (int j = 0; j < 4; ++j) jw[j] = f16bits(v[j]);
    *(u16x4*)(jk + idx) = jw;
  } else {
    u16x4 jold = *(const u16x4*)(jk + idx);
    f32x4 jv;
#pragma unroll
    for (int j = 0; j < 4; ++j) jv[j] = fmaxf(f16val(jold[j]), v[j]);
    if (mode == 1) {
      u16x4 jw;
#pragma unroll
      for (int j = 0; j < 4; ++j) jw[j] = f16bits(jv[j]);
      *(u16x4*)(jk + idx) = jw;
    } else {
      pv = jv;
    }
  }

  float nout = norm_out[node];
  u16x4 hw;
#pragma unroll
  for (int j = 0; j < 4; ++j) hw[j] = f16bits(pv[j] * nout);
  *(u16x4*)(hF + idx) = hw;
}

// ---------------- final 40-dim aggregation + log_softmax (f16 proj, 40-packed) ----------------

__global__ __launch_bounds__(64) void k_agg_out(const u16* __restrict__ proj,
                                                const int* __restrict__ row_ptr,
                                                const int* __restrict__ csr_src,
                                                const float* __restrict__ norm_in,
                                                const float* __restrict__ b_out,
                                                float* __restrict__ out) {
  int n = blockIdx.x;
  int c = threadIdx.x;  // 64 threads, cols 0..39 live
  int s = row_ptr[n], e = row_ptr[n + 1];
  int cc = (c < 40) ? c : 39;
  float a0 = 0.f, a1 = 0.f, a2 = 0.f, a3 = 0.f;
  int i = s;
  for (; i + 3 < e; i += 4) {
    a0 += f16val(proj[(size_t)csr_src[i] * 40 + cc]);
    a1 += f16val(proj[(size_t)csr_src[i + 1] * 40 + cc]);
    a2 += f16val(proj[(size_t)csr_src[i + 2] * 40 + cc]);
    a3 += f16val(proj[(size_t)csr_src[i + 3] * 40 + cc]);
  }
  for (; i < e; ++i) a0 += f16val(proj[(size_t)csr_src[i] * 40 + cc]);
  float acc = (a0 + a1) + (a2 + a3);
  float v = acc * norm_in[n] + ((c < 40) ? b_out[c] : 0.f);
  float vm = (c < 40) ? v : -3.0e38f;
  float m = vm;
#pragma unroll
  for (int o = 32; o > 0; o >>= 1) m = fmaxf(m, __shfl_xor(m, o, 64));
  float ex = (c < 40) ? __expf(v - m) : 0.f;
  float ssum = ex;
#pragma unroll
  for (int o = 32; o > 0; o >>= 1) ssum += __shfl_xor(ssum, o, 64);
  float lse = m + logf(ssum);
  if (c < 40) out[(size_t)n * 40 + c] = v - lse;
}

// ---------------- launch ----------------

extern "C" void kernel_launch(void* const* d_in, const int* in_sizes, int n_in,
                              void* d_out, int out_size, void* d_ws, size_t ws_size,
                              hipStream_t stream) {
  const float* feats = (const float*)d_in[0];
  const int*   src   = (const int*)d_in[1];
  const int*   dst   = (const int*)d_in[2];
  const float* W0    = (const float*)d_in[3];
  const float* b0    = (const float*)d_in[4];
  const float* Ws    = (const float*)d_in[5];
  const float* bs    = (const float*)d_in[6];
  const float* W_out = (const float*)d_in[7];
  const float* b_out = (const float*)d_in[8];
  float* out = (float*)d_out;

  char* base = (char*)d_ws;
  size_t off = 0;
  auto alloc = [&](size_t bytes) -> void* {
    off = (off + 255) & ~(size_t)255;
    void* r = base + off;
    off += bytes;
    return r;
  };
  float* norm_out = (float*)alloc((size_t)N_NODES * 4);
  float* norm_in  = (float*)alloc((size_t)N_NODES * 4);
  int*   deg_out  = (int*)alloc((size_t)N_NODES * 4);
  int*   deg_in   = (int*)alloc((size_t)N_NODES * 4);
  int*   cursor   = (int*)alloc((size_t)N_NODES * 4);
  int*   row_ptr  = (int*)alloc((size_t)(N_NODES + 1) * 4);
  int*   bsum     = (int*)alloc((size_t)SCAN_NB * 4);
  int*   boffs    = (int*)alloc((size_t)SCAN_NB * 4);
  int*   csr_src  = (int*)alloc((size_t)N_EDGES * 4);
  u16*   Wt0      = (u16*)alloc((size_t)256 * 512 * 2);
  u16*   Wts      = (u16*)alloc((size_t)5 * 256 * 256 * 2);
  u16*   Wto      = (u16*)alloc((size_t)128 * 256 * 2);
  u16*   proj40   = (u16*)alloc((size_t)N_NODES * 40 * 2 + 256);
  u16*   hF       = (u16*)alloc((size_t)N_NODES * 256 * 2);
  u16*   bufC     = (u16*)alloc((size_t)N_NODES * 256 * 2);
  u16*   jk       = (u16*)alloc((size_t)N_NODES * 256 * 2);
  (void)ws_size; (void)in_sizes; (void)n_in; (void)out_size;

  hipMemsetAsync(deg_out, 0, (size_t)N_NODES * 4, stream);
  hipMemsetAsync(deg_in,  0, (size_t)N_NODES * 4, stream);
  hipMemsetAsync(cursor,  0, (size_t)N_NODES * 4, stream);

  k_count<<<2048, 256, 0, stream>>>(src, dst, deg_out, deg_in);
  k_norms<<<(N_NODES + 255) / 256, 256, 0, stream>>>(deg_out, deg_in, norm_out, norm_in);
  k_scan1<<<SCAN_NB, 1024, 0, stream>>>(deg_in, bsum);
  k_scan2<<<1, 128, 0, stream>>>(bsum, boffs);
  k_scan3<<<SCAN_NB, 1024, 0, stream>>>(deg_in, boffs, row_ptr);
  k_fill<<<2048, 256, 0, stream>>>(src, dst, row_ptr, cursor, csr_src);

  k_wconv<<<(256 * 512 + 255) / 256, 256, 0, stream>>>(W0, 512, 256, 256, Wt0);
  for (int ll = 0; ll < 5; ++ll)
    k_wconv<<<(256 * 256 + 255) / 256, 256, 0, stream>>>(
        Ws + (size_t)ll * 256 * 256, 256, 256, 256, Wts + (size_t)ll * 256 * 256);
  k_wconv<<<(128 * 256 + 255) / 256, 256, 0, stream>>>(W_out, 256, 40, 128, Wto);

  const int NBROW = (N_NODES + 127) / 128;  // 782
  dim3 ga((N_NODES + 3) / 4);
  // layer 0 (K=512, f32 A with register prefetch; pair-swizzled grid)
  k_gemm_l0<<<NBROW * 2, 256, 0, stream>>>(feats, 512, Wt0,
                                           norm_out, bufC, 256, N_NODES, 256, NBROW);
  k_agg<<<ga, 256, 0, stream>>>(bufC, row_ptr, csr_src, norm_in, norm_out, b0,
                                hF, jk, 0);
  // layers 1..5 (K=256, f16 plane A, 3-buf pipelined + XCD pair-swizzle)
  for (int ll = 0; ll < 5; ++ll) {
    k_gemm_p<2, 0><<<NBROW * 2, 256, 0, stream>>>(hF, 256,
                                                  Wts + (size_t)ll * 256 * 256,
                                                  bufC, 256, N_NODES, 256, NBROW);
    int mode = (ll == 4) ? 2 : 1;
    const float* bias = bs + (size_t)ll * 256;
    k_agg<<<ga, 256, 0, stream>>>(bufC, row_ptr, csr_src, norm_in, norm_out, bias,
                                  hF, jk, mode);
  }
  // final: jk planes (mode-2 agg) @ W_out -> f16 proj40 (40-packed), agg + log_softmax
  k_gemm_p<1, 0><<<NBROW, 256, 0, stream>>>(hF, 256, Wto,
                                            proj40, 40, N_NODES, 40, NBROW);
  k_agg_out<<<N_NODES, 64, 0, stream>>>(proj40, row_ptr, csr_src, norm_in, b_out, out);
}

// Round 17
// 1367.599 us; speedup vs baseline: 1.0289x; 1.0289x over previous
//
#include <hip/hip_runtime.h>
#include <hip/hip_bf16.h>
#include <math.h>

#define N_NODES 100000
#define N_EDGES 1600000
#define SCAN_B 1024
#define SCAN_NB ((N_NODES + SCAN_B - 1) / SCAN_B)

typedef _Float16 f16;
typedef f16 f16x8 __attribute__((ext_vector_type(8)));
typedef float f32x4 __attribute__((ext_vector_type(4)));
typedef unsigned short u16;
typedef u16 u16x8 __attribute__((ext_vector_type(8)));
typedef u16 u16x4 __attribute__((ext_vector_type(4)));

__device__ __forceinline__ u16 f16bits(float f) {
  union { f16 h; u16 u; } c; c.h = (f16)f; return c.u;
}
__device__ __forceinline__ float f16val(u16 b) {
  union { u16 u; f16 h; } c; c.u = b; return (float)c.h;
}

// async global->LDS, 16B per lane; LDS dest = wave-uniform base + lane*16
__device__ __forceinline__ void gload16(const void* g, void* l) {
  __builtin_amdgcn_global_load_lds(
      (const __attribute__((address_space(1))) void*)g,
      (__attribute__((address_space(3))) void*)l, 16, 0, 0);
}

// XCD pair-swizzle: ids p and p+8 (same XCD under round-robin) share a row-stripe.
__device__ __forceinline__ void pair_map(int p, int NBrow, int& row, int& col) {
  int nb = NBrow * 2;
  int cut = (nb >> 4) << 4;
  if (p < cut) { row = ((p >> 4) << 3) + (p & 7); col = (p >> 3) & 1; }
  else { int q = p - cut; row = (cut >> 1) + (q >> 1); col = q & 1; }
}

// ---------------- graph prep ----------------

__global__ void k_count(const int* __restrict__ src, const int* __restrict__ dst,
                        int* __restrict__ deg_out, int* __restrict__ deg_in) {
  int i = blockIdx.x * blockDim.x + threadIdx.x;
  int stride = gridDim.x * blockDim.x;
  for (; i < N_EDGES; i += stride) {
    atomicAdd(&deg_out[src[i]], 1);
    atomicAdd(&deg_in[dst[i]], 1);
  }
}

__global__ void k_norms(const int* __restrict__ deg_out, const int* __restrict__ deg_in,
                        float* __restrict__ norm_out, float* __restrict__ norm_in) {
  int i = blockIdx.x * blockDim.x + threadIdx.x;
  if (i < N_NODES) {
    int a = deg_out[i], b = deg_in[i];
    norm_out[i] = a > 0 ? rsqrtf((float)a) : 0.f;
    norm_in[i]  = b > 0 ? rsqrtf((float)b) : 0.f;
  }
}

// hierarchical scan: block sums -> scan sums -> local scan + base
__global__ __launch_bounds__(1024) void k_scan1(const int* __restrict__ deg,
                                                int* __restrict__ bsum) {
  __shared__ int red[16];
  int b = blockIdx.x, t = threadIdx.x;
  int i = b * SCAN_B + t;
  int x = (i < N_NODES) ? deg[i] : 0;
#pragma unroll
  for (int o = 32; o > 0; o >>= 1) x += __shfl_down(x, o, 64);
  if ((t & 63) == 0) red[t >> 6] = x;
  __syncthreads();
  if (t == 0) {
    int s = 0;
#pragma unroll
    for (int j = 0; j < 16; ++j) s += red[j];
    bsum[b] = s;
  }
}

__global__ __launch_bounds__(128) void k_scan2(const int* __restrict__ bsum,
                                               int* __restrict__ boffs) {
  __shared__ int buf[128];
  int t = threadIdx.x;
  int x = (t < SCAN_NB) ? bsum[t] : 0;
  buf[t] = x;
  __syncthreads();
  for (int off = 1; off < 128; off <<= 1) {
    int v = (t >= off) ? buf[t - off] : 0;
    __syncthreads();
    buf[t] += v;
    __syncthreads();
  }
  if (t < SCAN_NB) boffs[t] = (t > 0) ? buf[t - 1] : 0;
}

__global__ __launch_bounds__(1024) void k_scan3(const int* __restrict__ deg,
                                                const int* __restrict__ boffs,
                                                int* __restrict__ row_ptr) {
  __shared__ int buf[SCAN_B];
  int b = blockIdx.x, t = threadIdx.x;
  int i = b * SCAN_B + t;
  int x = (i < N_NODES) ? deg[i] : 0;
  buf[t] = x;
  __syncthreads();
  for (int off = 1; off < SCAN_B; off <<= 1) {
    int v = (t >= off) ? buf[t - off] : 0;
    __syncthreads();
    buf[t] += v;
    __syncthreads();
  }
  if (i < N_NODES) row_ptr[i + 1] = boffs[b] + buf[t];
  if (i == 0) row_ptr[0] = 0;
}

// ---- XCD-sharded CSR fill ----
// Group g = blockIdx.x & 7 (= XCD under round-robin dispatch). Group g processes
// only edges with dst in range [g*12500, (g+1)*12500): all writes to a CSR line
// come from ONE XCD -> the line coalesces in that XCD's L2 instead of
// ping-ponging (round-13 k_fill: 108 MB writes for 6.4 MB of data). The edge
// list is logically read 8x but is 12.8 MB -> L3-resident after first touch.

__global__ void k_fill_x(const int* __restrict__ src, const int* __restrict__ dst,
                         const int* __restrict__ row_ptr, int* __restrict__ cursor,
                         int* __restrict__ csr_src) {
  unsigned g = blockIdx.x & 7u;
  int gb = blockIdx.x >> 3;                    // rank within group (0..255)
  int i = gb * 256 + threadIdx.x;
  const int stride = 256 * 256;                // 256 blocks/group * 256 threads
  for (; i < N_EDGES; i += stride) {
    int d = dst[i];
    if ((unsigned)(d * 8u) / 100000u != g) continue;
    int p = atomicAdd(&cursor[d], 1);
    csr_src[row_ptr[d] + p] = src[i];
  }
}

// transpose + f16 convert: W[K][N] f32 -> Wt[NB][K] f16 (bits in u16)
__global__ void k_wconv(const float* __restrict__ W, int K, int N, int NB,
                        u16* __restrict__ Wt) {
  int i = blockIdx.x * blockDim.x + threadIdx.x;
  if (i >= NB * K) return;
  int col = i / K, k = i - col * K;
  float v = (col < N) ? W[(size_t)k * N + col] : 0.f;
  Wt[i] = f16bits(v);
}

// ---------------- pipelined f16 MFMA GEMM: 3-buffer, 2-deep prefetch ----------------

template <int NBCOL, int OUTF32>
__global__ __launch_bounds__(256) void k_gemm_p(
    const u16* __restrict__ Ax, int K,
    const u16* __restrict__ Bx,
    void* __restrict__ Cv, int ldc, int M, int Ncols, int NBrow) {
  __shared__ u16 sA[3][8][4][16][8];
  __shared__ u16 sB[3][8][4][16][8];

  int p = blockIdx.x;
  int row, col;
  if (NBCOL == 2) pair_map(p, NBrow, row, col);
  else { row = p; col = 0; }
  int rowBase = row * 128;
  int colBase = col * 128;

  int t = threadIdx.x;
  int w = t >> 6, l = t & 63;
  int lr = l & 15;
  int kc = l >> 4;

  int gaR0 = min(rowBase + w * 16 + lr, M - 1);
  int gaR1 = min(rowBase + (4 + w) * 16 + lr, M - 1);
  int gbR0 = colBase + w * 16 + lr;
  int gbR1 = colBase + (4 + w) * 16 + lr;

  const u16* pA0 = Ax + (size_t)gaR0 * K + kc * 8;
  const u16* pA1 = Ax + (size_t)gaR1 * K + kc * 8;
  const u16* pB0 = Bx + (size_t)gbR0 * K + kc * 8;
  const u16* pB1 = Bx + (size_t)gbR1 * K + kc * 8;

  int wr = (w >> 1) * 64, wc = (w & 1) * 64;
  int rbA = (w >> 1) * 4;
  int rbB = (w & 1) * 4;
  int crow = kc * 4;

  f32x4 acc[4][4];
#pragma unroll
  for (int r = 0; r < 4; ++r)
#pragma unroll
    for (int c = 0; c < 4; ++c) acc[r][c] = (f32x4)(0.f);

  auto stage = [&](int bb, int k0) {
    gload16(pA0 + k0, &sA[bb][w][0][0][0]);
    gload16(pA1 + k0, &sA[bb][4 + w][0][0][0]);
    gload16(pB0 + k0, &sB[bb][w][0][0][0]);
    gload16(pB1 + k0, &sB[bb][4 + w][0][0][0]);
  };

  int NS = K >> 5;
  stage(0, 0);
  if (1 < NS) stage(1, 32);
  for (int s = 0; s < NS; ++s) {
    int bb = s % 3;
    if (s + 2 < NS) {
      stage((s + 2) % 3, (s + 2) * 32);
      asm volatile("s_waitcnt vmcnt(8)" ::: "memory");
    } else if (s + 1 < NS) {
      asm volatile("s_waitcnt vmcnt(4)" ::: "memory");
    } else {
      asm volatile("s_waitcnt vmcnt(0)" ::: "memory");
    }
    __builtin_amdgcn_s_barrier();

    f16x8 a[4], b[4];
#pragma unroll
    for (int r = 0; r < 4; ++r) a[r] = *(const f16x8*)&sA[bb][rbA + r][kc][lr][0];
#pragma unroll
    for (int c = 0; c < 4; ++c) b[c] = *(const f16x8*)&sB[bb][rbB + c][kc][lr][0];
#pragma unroll
    for (int r = 0; r < 4; ++r)
#pragma unroll
      for (int c = 0; c < 4; ++c)
        acc[r][c] = __builtin_amdgcn_mfma_f32_16x16x32_f16(a[r], b[c], acc[r][c], 0, 0, 0);

    __builtin_amdgcn_s_barrier();
  }

#pragma unroll
  for (int r = 0; r < 4; ++r)
#pragma unroll
    for (int c = 0; c < 4; ++c) {
      int ccol = colBase + wc + c * 16 + lr;
      if (ccol < Ncols) {
#pragma unroll
        for (int j = 0; j < 4; ++j) {
          int rrow = rowBase + wr + r * 16 + crow + j;
          if (rrow < M) {
            if (OUTF32) ((float*)Cv)[(size_t)rrow * ldc + ccol] = acc[r][c][j];
            else        ((u16*)Cv)[(size_t)rrow * ldc + ccol] = f16bits(acc[r][c][j]);
          }
        }
      }
    }
}

// ---------------- layer-0 GEMM: f32 A with register prefetch ----------------

__global__ __launch_bounds__(256) void k_gemm_l0(
    const float* __restrict__ Af, int K,
    const u16* __restrict__ Bx,
    const float* __restrict__ rowscale,
    u16* __restrict__ C, int ldc, int M, int Ncols, int NBrow) {
  __shared__ u16 sA[8][4][16][8];
  __shared__ u16 sB[8][4][16][8];

  int row, col;
  pair_map(blockIdx.x, NBrow, row, col);
  int rowBase = row * 128;
  int colBase = col * 128;

  int t = threadIdx.x;
  int w = t >> 6, l = t & 63;
  int lr = l & 15;
  int kc = l >> 4;

  int gaR0 = min(rowBase + w * 16 + lr, M - 1);
  int gaR1 = min(rowBase + (4 + w) * 16 + lr, M - 1);
  int gbR0 = colBase + w * 16 + lr;
  int gbR1 = colBase + (4 + w) * 16 + lr;

  const float* pA0 = Af + (size_t)gaR0 * K + kc * 8;
  const float* pA1 = Af + (size_t)gaR1 * K + kc * 8;
  float rs0 = rowscale[gaR0], rs1 = rowscale[gaR1];

  int wr = (w >> 1) * 64, wc = (w & 1) * 64;
  int rbA = (w >> 1) * 4;
  int rbB = (w & 1) * 4;
  int crow = kc * 4;

  f32x4 acc[4][4];
#pragma unroll
  for (int r = 0; r < 4; ++r)
#pragma unroll
    for (int c = 0; c < 4; ++c) acc[r][c] = (f32x4)(0.f);

  float4 r00 = *(const float4*)(pA0);
  float4 r01 = *(const float4*)(pA0 + 4);
  float4 r10 = *(const float4*)(pA1);
  float4 r11 = *(const float4*)(pA1 + 4);

  int NS = K >> 5;
  for (int s = 0; s < NS; ++s) {
    int k0 = s * 32;
    __builtin_amdgcn_s_barrier();
    asm volatile("s_waitcnt vmcnt(0)" ::: "memory");
    u16x8 h;
    h[0] = f16bits(r00.x * rs0); h[1] = f16bits(r00.y * rs0);
    h[2] = f16bits(r00.z * rs0); h[3] = f16bits(r00.w * rs0);
    h[4] = f16bits(r01.x * rs0); h[5] = f16bits(r01.y * rs0);
    h[6] = f16bits(r01.z * rs0); h[7] = f16bits(r01.w * rs0);
    *(u16x8*)&sA[w][kc][lr][0] = h;
    h[0] = f16bits(r10.x * rs1); h[1] = f16bits(r10.y * rs1);
    h[2] = f16bits(r10.z * rs1); h[3] = f16bits(r10.w * rs1);
    h[4] = f16bits(r11.x * rs1); h[5] = f16bits(r11.y * rs1);
    h[6] = f16bits(r11.z * rs1); h[7] = f16bits(r11.w * rs1);
    *(u16x8*)&sA[4 + w][kc][lr][0] = h;
    gload16(Bx + (size_t)gbR0 * K + k0 + kc * 8, &sB[w][0][0][0]);
    gload16(Bx + (size_t)gbR1 * K + k0 + kc * 8, &sB[4 + w][0][0][0]);
    if (s + 1 < NS) {
      int kn = k0 + 32;
      r00 = *(const float4*)(pA0 + kn);
      r01 = *(const float4*)(pA0 + kn + 4);
      r10 = *(const float4*)(pA1 + kn);
      r11 = *(const float4*)(pA1 + kn + 4);
      asm volatile("s_waitcnt vmcnt(4) lgkmcnt(0)" ::: "memory");
    } else {
      asm volatile("s_waitcnt vmcnt(0) lgkmcnt(0)" ::: "memory");
    }
    __builtin_amdgcn_s_barrier();

    f16x8 a[4], b[4];
#pragma unroll
    for (int r = 0; r < 4; ++r) a[r] = *(const f16x8*)&sA[rbA + r][kc][lr][0];
#pragma unroll
    for (int c = 0; c < 4; ++c) b[c] = *(const f16x8*)&sB[rbB + c][kc][lr][0];
#pragma unroll
    for (int r = 0; r < 4; ++r)
#pragma unroll
      for (int c = 0; c < 4; ++c)
        acc[r][c] = __builtin_amdgcn_mfma_f32_16x16x32_f16(a[r], b[c], acc[r][c], 0, 0, 0);
  }

#pragma unroll
  for (int r = 0; r < 4; ++r)
#pragma unroll
    for (int c = 0; c < 4; ++c) {
      int ccol = colBase + wc + c * 16 + lr;
      if (ccol < Ncols) {
#pragma unroll
        for (int j = 0; j < 4; ++j) {
          int rrow = rowBase + wr + r * 16 + crow + j;
          if (rrow < M) C[(size_t)rrow * ldc + ccol] = f16bits(acc[r][c][j]);
        }
      }
    }
}

// ---------------- CSR aggregation: wave per node, lane owns 4 cols ----------------

__global__ __launch_bounds__(256) void k_agg(const u16* __restrict__ proj,
                                             const int* __restrict__ row_ptr,
                                             const int* __restrict__ csr_src,
                                             const float* __restrict__ norm_in,
                                             const float* __restrict__ norm_out,
                                             const float* __restrict__ bias,
                                             u16* __restrict__ hF,
                                             u16* __restrict__ jk, int mode) {
  int wid = __builtin_amdgcn_readfirstlane(threadIdx.x >> 6);
  int node = blockIdx.x * 4 + wid;
  if (node >= N_NODES) return;
  int l4 = (threadIdx.x & 63) * 4;

  int s = row_ptr[node], e = row_ptr[node + 1];
  f32x4 a0 = (f32x4)(0.f), a1 = (f32x4)(0.f), a2 = (f32x4)(0.f), a3 = (f32x4)(0.f);
  int i = s;
  for (; i + 7 < e; i += 8) {
    int u0 = csr_src[i + 0], u1 = csr_src[i + 1], u2 = csr_src[i + 2], u3 = csr_src[i + 3];
    int u4 = csr_src[i + 4], u5 = csr_src[i + 5], u6 = csr_src[i + 6], u7 = csr_src[i + 7];
    u16x4 r0 = *(const u16x4*)(proj + (size_t)u0 * 256 + l4);
    u16x4 r1 = *(const u16x4*)(proj + (size_t)u1 * 256 + l4);
    u16x4 r2 = *(const u16x4*)(proj + (size_t)u2 * 256 + l4);
    u16x4 r3 = *(const u16x4*)(proj + (size_t)u3 * 256 + l4);
    u16x4 r4 = *(const u16x4*)(proj + (size_t)u4 * 256 + l4);
    u16x4 r5 = *(const u16x4*)(proj + (size_t)u5 * 256 + l4);
    u16x4 r6 = *(const u16x4*)(proj + (size_t)u6 * 256 + l4);
    u16x4 r7 = *(const u16x4*)(proj + (size_t)u7 * 256 + l4);
#pragma unroll
    for (int j = 0; j < 4; ++j) {
      a0[j] += f16val(r0[j]) + f16val(r4[j]);
      a1[j] += f16val(r1[j]) + f16val(r5[j]);
      a2[j] += f16val(r2[j]) + f16val(r6[j]);
      a3[j] += f16val(r3[j]) + f16val(r7[j]);
    }
  }
  for (; i + 3 < e; i += 4) {
    int u0 = csr_src[i + 0], u1 = csr_src[i + 1], u2 = csr_src[i + 2], u3 = csr_src[i + 3];
    u16x4 r0 = *(const u16x4*)(proj + (size_t)u0 * 256 + l4);
    u16x4 r1 = *(const u16x4*)(proj + (size_t)u1 * 256 + l4);
    u16x4 r2 = *(const u16x4*)(proj + (size_t)u2 * 256 + l4);
    u16x4 r3 = *(const u16x4*)(proj + (size_t)u3 * 256 + l4);
#pragma unroll
    for (int j = 0; j < 4; ++j) {
      a0[j] += f16val(r0[j]);
      a1[j] += f16val(r1[j]);
      a2[j] += f16val(r2[j]);
      a3[j] += f16val(r3[j]);
    }
  }
  for (; i < e; ++i) {
    u16x4 r0 = *(const u16x4*)(proj + (size_t)csr_src[i] * 256 + l4);
#pragma unroll
    for (int j = 0; j < 4; ++j) a0[j] += f16val(r0[j]);
  }

  float nin = norm_in[node];
  f32x4 b4 = *(const f32x4*)(bias + l4);
  f32x4 v = ((a0 + a1) + (a2 + a3)) * nin + b4;
#pragma unroll
  for (int j = 0; j < 4; ++j) v[j] = fmaxf(v[j], 0.f);

  size_t idx = (size_t)node * 256 + l4;
  f32x4 pv = v;
  if (mode == 0) {
    u16x4 jw;
#pragma unroll
    for (int j = 0; j < 4; ++j) jw[j] = f16bits(v[j]);
    *(u16x4*)(jk + idx) = jw;
  } else {
    u16x4 jold = *(const u16x4*)(jk + idx);
    f32x4 jv;
#pragma unroll
    for (int j = 0; j < 4; ++j) jv[j] = fmaxf(f16val(jold[j]), v[j]);
    if (mode == 1) {
      u16x4 jw;
#pragma unroll
      for (int j = 0; j < 4; ++j) jw[j] = f16bits(jv[j]);
      *(u16x4*)(jk + idx) = jw;
    } else {
      pv = jv;
    }
  }

  float nout = norm_out[node];
  u16x4 hw;
#pragma unroll
  for (int j = 0; j < 4; ++j) hw[j] = f16bits(pv[j] * nout);
  *(u16x4*)(hF + idx) = hw;
}

// ---------------- final 40-dim aggregation + log_softmax (f16 proj, 40-packed) ----------------

__global__ __launch_bounds__(64) void k_agg_out(const u16* __restrict__ proj,
                                                const int* __restrict__ row_ptr,
                                                const int* __restrict__ csr_src,
                                                const float* __restrict__ norm_in,
                                                const float* __restrict__ b_out,
                                                float* __restrict__ out) {
  int n = blockIdx.x;
  int c = threadIdx.x;  // 64 threads, cols 0..39 live
  int s = row_ptr[n], e = row_ptr[n + 1];
  int cc = (c < 40) ? c : 39;
  float a0 = 0.f, a1 = 0.f, a2 = 0.f, a3 = 0.f;
  int i = s;
  for (; i + 3 < e; i += 4) {
    a0 += f16val(proj[(size_t)csr_src[i] * 40 + cc]);
    a1 += f16val(proj[(size_t)csr_src[i + 1] * 40 + cc]);
    a2 += f16val(proj[(size_t)csr_src[i + 2] * 40 + cc]);
    a3 += f16val(proj[(size_t)csr_src[i + 3] * 40 + cc]);
  }
  for (; i < e; ++i) a0 += f16val(proj[(size_t)csr_src[i] * 40 + cc]);
  float acc = (a0 + a1) + (a2 + a3);
  float v = acc * norm_in[n] + ((c < 40) ? b_out[c] : 0.f);
  float vm = (c < 40) ? v : -3.0e38f;
  float m = vm;
#pragma unroll
  for (int o = 32; o > 0; o >>= 1) m = fmaxf(m, __shfl_xor(m, o, 64));
  float ex = (c < 40) ? __expf(v - m) : 0.f;
  float ssum = ex;
#pragma unroll
  for (int o = 32; o > 0; o >>= 1) ssum += __shfl_xor(ssum, o, 64);
  float lse = m + logf(ssum);
  if (c < 40) out[(size_t)n * 40 + c] = v - lse;
}

// ---------------- launch ----------------

extern "C" void kernel_launch(void* const* d_in, const int* in_sizes, int n_in,
                              void* d_out, int out_size, void* d_ws, size_t ws_size,
                              hipStream_t stream) {
  const float* feats = (const float*)d_in[0];
  const int*   src   = (const int*)d_in[1];
  const int*   dst   = (const int*)d_in[2];
  const float* W0    = (const float*)d_in[3];
  const float* b0    = (const float*)d_in[4];
  const float* Ws    = (const float*)d_in[5];
  const float* bs    = (const float*)d_in[6];
  const float* W_out = (const float*)d_in[7];
  const float* b_out = (const float*)d_in[8];
  float* out = (float*)d_out;

  char* base = (char*)d_ws;
  size_t off = 0;
  auto alloc = [&](size_t bytes) -> void* {
    off = (off + 255) & ~(size_t)255;
    void* r = base + off;
    off += bytes;
    return r;
  };
  float* norm_out = (float*)alloc((size_t)N_NODES * 4);
  float* norm_in  = (float*)alloc((size_t)N_NODES * 4);
  int*   deg_out  = (int*)alloc((size_t)N_NODES * 4);
  int*   deg_in   = (int*)alloc((size_t)N_NODES * 4);
  int*   cursor   = (int*)alloc((size_t)N_NODES * 4);
  int*   row_ptr  = (int*)alloc((size_t)(N_NODES + 1) * 4);
  int*   bsum     = (int*)alloc((size_t)SCAN_NB * 4);
  int*   boffs    = (int*)alloc((size_t)SCAN_NB * 4);
  int*   csr_src  = (int*)alloc((size_t)N_EDGES * 4);
  u16*   Wt0      = (u16*)alloc((size_t)256 * 512 * 2);
  u16*   Wts      = (u16*)alloc((size_t)5 * 256 * 256 * 2);
  u16*   Wto      = (u16*)alloc((size_t)128 * 256 * 2);
  u16*   proj40   = (u16*)alloc((size_t)N_NODES * 40 * 2 + 256);
  u16*   hF       = (u16*)alloc((size_t)N_NODES * 256 * 2);
  u16*   bufC     = (u16*)alloc((size_t)N_NODES * 256 * 2);
  u16*   jk       = (u16*)alloc((size_t)N_NODES * 256 * 2);
  (void)ws_size; (void)in_sizes; (void)n_in; (void)out_size;

  hipMemsetAsync(deg_out, 0, (size_t)N_NODES * 4, stream);
  hipMemsetAsync(deg_in,  0, (size_t)N_NODES * 4, stream);
  hipMemsetAsync(cursor,  0, (size_t)N_NODES * 4, stream);

  k_count<<<2048, 256, 0, stream>>>(src, dst, deg_out, deg_in);
  k_norms<<<(N_NODES + 255) / 256, 256, 0, stream>>>(deg_out, deg_in, norm_out, norm_in);
  k_scan1<<<SCAN_NB, 1024, 0, stream>>>(deg_in, bsum);
  k_scan2<<<1, 128, 0, stream>>>(bsum, boffs);
  k_scan3<<<SCAN_NB, 1024, 0, stream>>>(deg_in, boffs, row_ptr);
  k_fill_x<<<2048, 256, 0, stream>>>(src, dst, row_ptr, cursor, csr_src);

  k_wconv<<<(256 * 512 + 255) / 256, 256, 0, stream>>>(W0, 512, 256, 256, Wt0);
  for (int ll = 0; ll < 5; ++ll)
    k_wconv<<<(256 * 256 + 255) / 256, 256, 0, stream>>>(
        Ws + (size_t)ll * 256 * 256, 256, 256, 256, Wts + (size_t)ll * 256 * 256);
  k_wconv<<<(128 * 256 + 255) / 256, 256, 0, stream>>>(W_out, 256, 40, 128, Wto);

  const int NBROW = (N_NODES + 127) / 128;  // 782
  dim3 ga((N_NODES + 3) / 4);
  // layer 0 (K=512, f32 A with register prefetch; pair-swizzled grid)
  k_gemm_l0<<<NBROW * 2, 256, 0, stream>>>(feats, 512, Wt0,
                                           norm_out, bufC, 256, N_NODES, 256, NBROW);
  k_agg<<<ga, 256, 0, stream>>>(bufC, row_ptr, csr_src, norm_in, norm_out, b0,
                                hF, jk, 0);
  // layers 1..5 (K=256, f16 plane A, 3-buf pipelined + XCD pair-swizzle)
  for (int ll = 0; ll < 5; ++ll) {
    k_gemm_p<2, 0><<<NBROW * 2, 256, 0, stream>>>(hF, 256,
                                                  Wts + (size_t)ll * 256 * 256,
                                                  bufC, 256, N_NODES, 256, NBROW);
    int mode = (ll == 4) ? 2 : 1;
    const float* bias = bs + (size_t)ll * 256;
    k_agg<<<ga, 256, 0, stream>>>(bufC, row_ptr, csr_src, norm_in, norm_out, bias,
                                  hF, jk, mode);
  }
  // final: jk planes (mode-2 agg) @ W_out -> f16 proj40 (40-packed), agg + log_softmax
  k_gemm_p<1, 0><<<NBROW, 256, 0, stream>>>(hF, 256, Wto,
                                            proj40, 40, N_NODES, 40, NBROW);
  k_agg_out<<<N_NODES, 64, 0, stream>>>(proj40, row_ptr, csr_src, norm_in, b_out, out);
}